// Round 8
// baseline (561.037 us; speedup 1.0000x reference)
//
#include <hip/hip_runtime.h>

#define NROWS 16384
#define DIM   1024
#define QSCALE 32.0f            // fp4 pre-scale 2^5
#define E8M0S  0x7A7A7A7Au      // 122 -> 2^-5 in every byte (both operands)
#define PSTRIDE 16384           // panel = 32 rows x 32 chunks x 16B

typedef int    v4i    __attribute__((ext_vector_type(4)));
typedef int    v8i    __attribute__((ext_vector_type(8)));
typedef float  f32x16 __attribute__((ext_vector_type(16)));

__device__ __forceinline__ float fexp2(float x) {
#if __has_builtin(__builtin_amdgcn_exp2f)
    return __builtin_amdgcn_exp2f(x);
#else
    return exp2f(x);
#endif
}
__device__ __forceinline__ float flog2(float x) {
#if __has_builtin(__builtin_amdgcn_logf)
    return __builtin_amdgcn_logf(x);
#else
    return log2f(x);
#endif
}

// fp4 e2m1 round-to-nearest encode of y (|y| clipped to 6).
__device__ __forceinline__ unsigned fp4_nib(float y) {
    unsigned s = (__float_as_uint(y) >> 31) << 3;
    float a = fminf(fabsf(y), 6.0f);
    unsigned c = (unsigned)(a >= 0.25f) + (unsigned)(a >= 0.75f) +
                 (unsigned)(a >= 1.25f) + (unsigned)(a >= 1.75f) +
                 (unsigned)(a >= 2.5f)  + (unsigned)(a >= 3.5f)  +
                 (unsigned)(a >= 5.0f);
    return c | s;
}

// Wave-per-row, grid-stride: L2-normalize img+txt (fp32), emit fp4 e2m1 in
// FRAGMENT-MAJOR panel layout: byte(row, c16, d) =
//   (row>>5)*16384 + c16*512 + (row&31)*16 + d,  d in [0,16): elements
//   c16*32 + 2d (low nibble), +1 (high nibble).
// A wave's MFMA fragment load is then base + lane*16 (coalesced 1KB), which
// eliminates LDS staging in the GEMM entirely. Also writes -z_ii to diagPart.
__global__ __launch_bounds__(256) void norm_fused(
    const float* __restrict__ img,
    const float* __restrict__ txt,
    unsigned char* __restrict__ imgQ,   // [512 panels][16384 B]
    unsigned char* __restrict__ txtQ,
    const float* __restrict__ lscale,
    const float* __restrict__ lbias,
    float* __restrict__ diagPart) {
    const int t    = threadIdx.x;
    const int lane = t & 63;
    const int wave = t >> 6;
    const int gw   = blockIdx.x * 4 + wave;   // 8192 waves total
    const float sc   = __expf(lscale[0]);
    const float bias = lbias[0];

    for (int row = gw; row < NROWS; row += 8192) {
        const float4* pi = (const float4*)(img + (size_t)row * DIM);
        const float4* pt = (const float4*)(txt + (size_t)row * DIM);
        float4 vi[4], vt[4];
        float ssi = 0.0f, sst = 0.0f, dot = 0.0f;
        #pragma unroll
        for (int j = 0; j < 4; ++j) {       // coalesced: lane + 64j
            vi[j] = pi[lane + 64 * j];
            vt[j] = pt[lane + 64 * j];
            ssi += vi[j].x*vi[j].x + vi[j].y*vi[j].y + vi[j].z*vi[j].z + vi[j].w*vi[j].w;
            sst += vt[j].x*vt[j].x + vt[j].y*vt[j].y + vt[j].z*vt[j].z + vt[j].w*vt[j].w;
            dot += vi[j].x*vt[j].x + vi[j].y*vt[j].y + vi[j].z*vt[j].z + vi[j].w*vt[j].w;
        }
        #pragma unroll
        for (int off = 1; off < 64; off <<= 1) {
            ssi += __shfl_xor(ssi, off, 64);
            sst += __shfl_xor(sst, off, 64);
            dot += __shfl_xor(dot, off, 64);
        }
        const float ii = 1.0f / fmaxf(sqrtf(ssi), 1e-12f);
        const float it = 1.0f / fmaxf(sqrtf(sst), 1e-12f);
        if (lane == 0) diagPart[row] = -fmaf(sc, dot * ii * it, bias);

        const float qi = ii * QSCALE, qt = it * QSCALE;
        // lane l, iter j holds elements 4*(l+64j)+{0..3} -> chunk c16=(l>>3)+8j,
        // halfword d2 = l&7 within the chunk's 16 bytes.
        unsigned char* qib = imgQ + (size_t)(row >> 5) * PSTRIDE + (row & 31) * 16
                           + (lane & 7) * 2;
        unsigned char* qtb = txtQ + (size_t)(row >> 5) * PSTRIDE + (row & 31) * 16
                           + (lane & 7) * 2;
        const int cbase = (lane >> 3) * 512;
        #pragma unroll
        for (int j = 0; j < 4; ++j) {
            unsigned p = fp4_nib(vi[j].x * qi)        | (fp4_nib(vi[j].y * qi) << 4) |
                         (fp4_nib(vi[j].z * qi) << 8) | (fp4_nib(vi[j].w * qi) << 12);
            unsigned q = fp4_nib(vt[j].x * qt)        | (fp4_nib(vt[j].y * qt) << 4) |
                         (fp4_nib(vt[j].z * qt) << 8) | (fp4_nib(vt[j].w * qt) << 12);
            *(ushort*)(qib + cbase + j * (8 * 512)) = (ushort)p;
            *(ushort*)(qtb + cbase + j * (8 * 512)) = (ushort)q;
        }
    }
}

// ZERO-BARRIER MX-fp4 GEMM: fragments load directly global->register from the
// fragment-major layout (one coalesced dwordx4 per fragment). No LDS staging,
// no __syncthreads in the K-loop -> compiler emits fine-grained vmcnt(N),
// MFMA<->load interleave (AITER-style), waves fully independent.
// Block 256x128, 4 waves 2x2, wave tile 128x64 = 4x2 of 32x32x64.
__global__ __launch_bounds__(256) void siglip_gemm(
    const unsigned char* __restrict__ A,
    const unsigned char* __restrict__ B,
    const float* __restrict__ lscale,
    const float* __restrict__ lbias,
    float* __restrict__ gemmPart)
{
    __shared__ float wred[4];

    const int t    = threadIdx.x;
    const int lane = t & 63;
    const int wave = t >> 6;
    const int wr   = wave >> 1;     // A half (128 rows = 4 panels)
    const int wc   = wave & 1;      // B half (64 cols = 2 panels)

    // grid 64 (M) x 128 (N); group-of-16 M-tiles for L2/L3 locality
    const int GRID_N = NROWS / 128;   // 128
    const int GM = 16;
    int b = blockIdx.x;
    int group = b / (GM * GRID_N);
    int ing   = b % (GM * GRID_N);
    int brow  = group * GM + (ing % GM);   // 0..63
    int bcol  = ing / GM;                  // 0..127

    // fragment pointers: step c2 reads 16B at +c2*1024 (chunk pair c2*2 + h,
    // h = lane>>5 folded into lane*16)
    const unsigned char* aF[4];
    const unsigned char* bF[2];
    #pragma unroll
    for (int i = 0; i < 4; ++i)
        aF[i] = A + (size_t)(brow * 8 + wr * 4 + i) * PSTRIDE + lane * 16;
    #pragma unroll
    for (int i = 0; i < 2; ++i)
        bF[i] = B + (size_t)(bcol * 4 + wc * 2 + i) * PSTRIDE + lane * 16;

    f32x16 acc[4][2] = {};

    #pragma unroll 4
    for (int c2 = 0; c2 < 16; ++c2) {
        const int off = c2 * 1024;
        v4i a0 = *(const v4i*)(aF[0] + off);
        v4i a1 = *(const v4i*)(aF[1] + off);
        v4i a2 = *(const v4i*)(aF[2] + off);
        v4i a3 = *(const v4i*)(aF[3] + off);
        v4i b0 = *(const v4i*)(bF[0] + off);
        v4i b1 = *(const v4i*)(bF[1] + off);
        v8i af[4], bf[2];
        af[0] = __builtin_shufflevector(a0, a0, 0, 1, 2, 3, -1, -1, -1, -1);
        af[1] = __builtin_shufflevector(a1, a1, 0, 1, 2, 3, -1, -1, -1, -1);
        af[2] = __builtin_shufflevector(a2, a2, 0, 1, 2, 3, -1, -1, -1, -1);
        af[3] = __builtin_shufflevector(a3, a3, 0, 1, 2, 3, -1, -1, -1, -1);
        bf[0] = __builtin_shufflevector(b0, b0, 0, 1, 2, 3, -1, -1, -1, -1);
        bf[1] = __builtin_shufflevector(b1, b1, 0, 1, 2, 3, -1, -1, -1, -1);
        #pragma unroll
        for (int mi = 0; mi < 4; ++mi)
            #pragma unroll
            for (int ni = 0; ni < 2; ++ni)
                acc[mi][ni] = __builtin_amdgcn_mfma_scale_f32_32x32x64_f8f6f4(
                    af[mi], bf[ni], acc[mi][ni],
                    4, 4,                     // cbsz=fp4(e2m1), blgp=fp4
                    0, (int)E8M0S,
                    0, (int)E8M0S);
    }

    // Epilogue: softplus(z) over all elements (label=-1 form); diagonal fixed
    // by -z_ii. Group-of-4 log trick (t <= ~31, product < 2^125: safe).
    const float l2e   = 1.44269504088896341f;
    const float scale = __expf(lscale[0]);
    const float aCo   = scale * l2e;
    const float bCo   = lbias[0] * l2e;
    float local = 0.0f;
    #pragma unroll
    for (int mi = 0; mi < 4; ++mi)
        #pragma unroll
        for (int ni = 0; ni < 2; ++ni)
            #pragma unroll
            for (int r = 0; r < 16; r += 4) {
                float e0 = fexp2(fmaf(aCo, acc[mi][ni][r + 0], bCo));
                float e1 = fexp2(fmaf(aCo, acc[mi][ni][r + 1], bCo));
                float e2 = fexp2(fmaf(aCo, acc[mi][ni][r + 2], bCo));
                float e3 = fexp2(fmaf(aCo, acc[mi][ni][r + 3], bCo));
                float p  = ((1.0f + e0) * (1.0f + e1)) *
                           ((1.0f + e2) * (1.0f + e3));
                local += flog2(p);
            }

    #pragma unroll
    for (int off = 32; off > 0; off >>= 1) local += __shfl_down(local, off, 64);
    if (lane == 0) wred[wave] = local;
    __syncthreads();
    if (t == 0)
        gemmPart[blockIdx.x] =
            (wred[0] + wred[1] + wred[2] + wred[3]) * 0.69314718055994531f;
}

// Sum 24576 partials (diagPart 16384 ++ gemmPart 8192, contiguous) -> loss.
__global__ __launch_bounds__(1024) void finalize_kernel(
    const float* __restrict__ parts, float* __restrict__ out) {
    __shared__ float wr[16];
    const int t    = threadIdx.x;
    const int lane = t & 63;
    const int wave = t >> 6;
    const float4* p4 = (const float4*)parts;   // 6144 float4
    float s = 0.0f;
    for (int i = t; i < 6144; i += 1024) {
        float4 v = p4[i];
        s += v.x + v.y + v.z + v.w;
    }
    #pragma unroll
    for (int off = 32; off > 0; off >>= 1) s += __shfl_down(s, off, 64);
    if (lane == 0) wr[wave] = s;
    __syncthreads();
    if (t == 0) {
        float tot = 0.0f;
        #pragma unroll
        for (int i = 0; i < 16; ++i) tot += wr[i];
        out[0] = tot / 268435456.0f;   // / N^2
    }
}

extern "C" void kernel_launch(void* const* d_in, const int* in_sizes, int n_in,
                              void* d_out, int out_size, void* d_ws, size_t ws_size,
                              hipStream_t stream) {
    const float* img    = (const float*)d_in[0];
    const float* txt    = (const float*)d_in[1];
    const float* lscale = (const float*)d_in[2];
    const float* lbias  = (const float*)d_in[3];
    float* out = (float*)d_out;

    char* ws = (char*)d_ws;
    unsigned char* imgQ = (unsigned char*)ws;                          // 8 MB
    unsigned char* txtQ = (unsigned char*)(ws + (size_t)NROWS * 512);  // 8 MB
    float* parts   = (float*)(ws + (size_t)2 * NROWS * 512);           // 24576 floats
    float* diagPart = parts;
    float* gemmPart = parts + NROWS;

    norm_fused<<<2048, 256, 0, stream>>>(img, txt, imgQ, txtQ, lscale, lbias, diagPart);
    siglip_gemm<<<dim3((NROWS / 256) * (NROWS / 128)), 256, 0, stream>>>(
        imgQ, txtQ, lscale, lbias, gemmPart);
    finalize_kernel<<<1, 1024, 0, stream>>>(parts, out);
}